// Round 13
// baseline (171.568 us; speedup 1.0000x reference)
//
#include <hip/hip_runtime.h>
#include <hip/hip_bf16.h>

#define NEG_SLOPE 0.2f
#define EPSF 1e-16f
#define BSH 8           // 256 nodes per bucket
#define BCAP 8192       // per-bucket arena capacity (u32 pairs)

typedef __attribute__((ext_vector_type(8))) short short8;     // 8 bf16 = 4 VGPR
typedef __attribute__((ext_vector_type(4))) float floatx4;    // MFMA acc

__device__ __forceinline__ float bf2f(unsigned short u) {
  union { unsigned int i; float f; } v; v.i = ((unsigned int)u) << 16; return v.f;
}
__device__ __forceinline__ unsigned short f2bf(float f) {
  union { float f; unsigned int i; } v; v.f = f;
  unsigned int r = v.i + 0x7fffu + ((v.i >> 16) & 1u);  // RNE
  return (unsigned short)(r >> 16);
}

// ---------------- merged prep: zero padded bucket cursors | detect+pack -----------------
__global__ __launch_bounds__(256) void prep_k(const unsigned short* __restrict__ xw,
                                              const void* __restrict__ w,
                                              const void* __restrict__ att,
                                              const void* __restrict__ bias,
                                              int* __restrict__ flag,
                                              int* __restrict__ bcur,
                                              int* __restrict__ ovf_cnt,
                                              unsigned short* __restrict__ bpack,
                                              unsigned short* __restrict__ wpack,
                                              float* __restrict__ bias_f,
                                              int nb16, int zb) {
  int b = blockIdx.x;
  if (b < zb) {
    int i = b * 256 + threadIdx.x;
    if (i < nb16) bcur[i] = 0;
    if (i == 0) *ovf_cnt = 0;
    return;
  }
  __shared__ int cnt;
  if (threadIdx.x == 0) cnt = 0;
  __syncthreads();
  // sample the 16 even bf16s of this thread's 64B span via 4 vector loads
  int local = 0;
  const uint4* xv4 = (const uint4*)(xw + threadIdx.x * 32);
#pragma unroll
  for (int k2 = 0; k2 < 4; k2++) {
    uint4 u = xv4[k2];
    unsigned uu[4] = {u.x, u.y, u.z, u.w};
#pragma unroll
    for (int q2 = 0; q2 < 4; q2++) {
      int ex = ((uu[q2] & 0xffffu) >> 7) & 0xFF;
      if (ex >= 0x90 || ex <= 0x40) local++;
    }
  }
  atomicAdd(&cnt, local);
  __syncthreads();
  int f32 = (cnt > 256) ? 1 : 0;
  int pb = b - zb;
  if (pb == 0 && threadIdx.x == 0) *flag = f32;
  if (pb < 128) {
    int i = pb * 256 + threadIdx.x;  // 0..32767
    int j = i & 7, lane = (i >> 3) & 63, nt = (i >> 9) & 7, kb = i >> 12;
    int f = (kb << 5) + ((lane >> 4) << 3) + j;
    int col = (nt << 4) + (lane & 15);
    int src = ((col >> 5) << 13) + (f << 5) + (col & 31);
    float v = f32 ? ((const float*)w)[src] : bf2f(((const unsigned short*)w)[src]);
    bpack[i] = f2bf(v);
  } else if (pb < 144) {
    int i = (pb - 128) * 256 + threadIdx.x;  // 0..4095
    int j = i & 7, lane = (i >> 3) & 63, kb = i >> 9;
    int quad = lane >> 4, m16 = lane & 15;
    int f = (kb << 5) + (quad << 3) + j;
    float v = 0.f;
    if (m16 < 8) {
      int hd = m16 & 3;
      int db = (m16 >= 4) ? 32 : 0;
      int wbase = (hd << 13) + (f << 5);
      int abase = (hd << 6) + db;
      float acc = 0.f;
      for (int c = 0; c < 32; c++) {
        float wv = f32 ? ((const float*)w)[wbase + c] : bf2f(((const unsigned short*)w)[wbase + c]);
        float av = f32 ? ((const float*)att)[abase + c] : bf2f(((const unsigned short*)att)[abase + c]);
        acc = fmaf(wv, av, acc);
      }
      v = acc;
    }
    wpack[i] = f2bf(v);
  } else {
    int i = threadIdx.x;
    if (i < 128) bias_f[i] = f32 ? ((const float*)bias)[i] : bf2f(((const unsigned short*)bias)[i]);
  }
}

// ---------------- fused: bf16-MFMA gemm+attlogits (blocks<gb) | bucket-run fill ---------
__global__ __launch_bounds__(256) void gemmfill_k(const void* __restrict__ xv,
                                                  const int* __restrict__ flag,
                                                  const unsigned short* __restrict__ bpack,
                                                  const unsigned short* __restrict__ wpack,
                                                  unsigned short* __restrict__ h,
                                                  float* __restrict__ a_srcp,
                                                  float* __restrict__ a_dstp,
                                                  const int* __restrict__ ei,
                                                  int* __restrict__ bcur,
                                                  unsigned int* __restrict__ arena,
                                                  int2* __restrict__ ovf,
                                                  int* __restrict__ ovf_cnt,
                                                  int n, int e, int gb, int fb) {
  int b = blockIdx.x;
  if (b < gb) {
    int t = threadIdx.x;
    int wave = t >> 6, l = t & 63;
    int quad = l >> 4, m16 = l & 15;
    long n0 = (long)b * 128 + wave * 32;
    int isf32 = *flag;

    floatx4 acc[2][8];
    floatx4 acca[2];
#pragma unroll
    for (int mt = 0; mt < 2; mt++) {
      acca[mt] = (floatx4){0.f, 0.f, 0.f, 0.f};
#pragma unroll
      for (int nt = 0; nt < 8; nt++) acc[mt][nt] = (floatx4){0.f, 0.f, 0.f, 0.f};
    }

    long rowA = n0 + m16;      if (rowA >= n) rowA = n - 1;   // clamp; discarded at store
    long rowB = n0 + 16 + m16; if (rowB >= n) rowB = n - 1;

    if (!isf32) {
      // ---- bf16: hoist ALL x loads (16 x 16B per lane), fully unrolled K loop ----
      short8 axr[8][2];
#pragma unroll
      for (int kb = 0; kb < 8; kb++) {
        axr[kb][0] = *(const short8*)((const unsigned short*)xv + (rowA << 8) + (kb << 5) + (quad << 3));
        axr[kb][1] = *(const short8*)((const unsigned short*)xv + (rowB << 8) + (kb << 5) + (quad << 3));
      }
#pragma unroll
      for (int kb = 0; kb < 8; kb++) {
        short8 wfr = *(const short8*)(wpack + (((kb << 6) + l) << 3));
        acca[0] = __builtin_amdgcn_mfma_f32_16x16x32_bf16(axr[kb][0], wfr, acca[0], 0, 0, 0);
        acca[1] = __builtin_amdgcn_mfma_f32_16x16x32_bf16(axr[kb][1], wfr, acca[1], 0, 0, 0);
#pragma unroll
        for (int nt = 0; nt < 8; nt++) {
          short8 bfr = *(const short8*)(bpack + (((kb << 3) + nt) << 9) + (l << 3));
          acc[0][nt] = __builtin_amdgcn_mfma_f32_16x16x32_bf16(axr[kb][0], bfr, acc[0][nt], 0, 0, 0);
          acc[1][nt] = __builtin_amdgcn_mfma_f32_16x16x32_bf16(axr[kb][1], bfr, acc[1][nt], 0, 0, 0);
        }
      }
    } else {
      // ---- f32: keep prefetch-1 structure (full hoist would spill) ----
      auto load_afr = [&](int kb, short8* dst) {
        long rows[2] = {rowA, rowB};
#pragma unroll
        for (int mt = 0; mt < 2; mt++) {
          const float* xp = (const float*)xv + (rows[mt] << 8) + (kb << 5) + (quad << 3);
          float4 u0 = *(const float4*)xp;
          float4 u1 = *(const float4*)(xp + 4);
          short8 a;
          a[0] = (short)f2bf(u0.x); a[1] = (short)f2bf(u0.y);
          a[2] = (short)f2bf(u0.z); a[3] = (short)f2bf(u0.w);
          a[4] = (short)f2bf(u1.x); a[5] = (short)f2bf(u1.y);
          a[6] = (short)f2bf(u1.z); a[7] = (short)f2bf(u1.w);
          dst[mt] = a;
        }
      };
      short8 afr[2], afn[2];
      load_afr(0, afr);
      for (int kb = 0; kb < 8; kb++) {
        short8 wfr = *(const short8*)(wpack + (((kb << 6) + l) << 3));
        short8 bfr[8];
#pragma unroll
        for (int nt = 0; nt < 8; nt++)
          bfr[nt] = *(const short8*)(bpack + (((kb << 3) + nt) << 9) + (l << 3));
        if (kb < 7) load_afr(kb + 1, afn);
        acca[0] = __builtin_amdgcn_mfma_f32_16x16x32_bf16(afr[0], wfr, acca[0], 0, 0, 0);
        acca[1] = __builtin_amdgcn_mfma_f32_16x16x32_bf16(afr[1], wfr, acca[1], 0, 0, 0);
#pragma unroll
        for (int nt = 0; nt < 8; nt++) {
          acc[0][nt] = __builtin_amdgcn_mfma_f32_16x16x32_bf16(afr[0], bfr[nt], acc[0][nt], 0, 0, 0);
          acc[1][nt] = __builtin_amdgcn_mfma_f32_16x16x32_bf16(afr[1], bfr[nt], acc[1][nt], 0, 0, 0);
        }
        afr[0] = afn[0]; afr[1] = afn[1];
      }
    }
#pragma unroll
    for (int mt = 0; mt < 2; mt++)
#pragma unroll
      for (int r = 0; r < 4; r++) {
        long row = n0 + mt * 16 + quad * 4 + r;
        if (row < n) {
#pragma unroll
          for (int nt = 0; nt < 8; nt++)
            h[(row << 7) + (nt << 4) + m16] = f2bf(acc[mt][nt][r]);
          if (m16 < 8) {
            float val = acca[mt][r];
            int hd = m16 & 3;
            if (m16 < 4) a_srcp[(row << 2) + hd] = val;
            else         a_dstp[(row << 2) + hd] = val;
          }
        }
      }
  } else {
    // -------- bucket-run fill: chunk = 4096 edges, 256-node buckets --------
    const int NB = (n + 255) >> BSH;        // <= 256 (n < 65536)
    __shared__ unsigned int lhist[256];
    __shared__ unsigned int gbase[256];
    int t = threadIdx.x;
    int c = b - gb;
    if (t < NB) lhist[t] = 0;
    __syncthreads();
    int e0 = c << 12;
    // issue ALL 32 edge loads upfront (dst+src unconditional, independent chains)
    unsigned dv[16]; int sv[16];
#pragma unroll
    for (int j = 0; j < 16; j++) {
      int i = e0 + (j << 8) + t;
      dv[j] = 0xFFFFFFFFu; sv[j] = 0;
      if (i < e) { dv[j] = (unsigned)ei[e + i]; sv[j] = ei[i]; }
    }
    unsigned pv[16];
    int lo[16];
#pragma unroll
    for (int j = 0; j < 16; j++) {
      pv[j] = 0xFFFF0000u;                  // invalid marker (d = 0xFFFF >= n)
      lo[j] = 0;
      if (dv[j] < (unsigned)n) {
        unsigned s = (unsigned)sv[j];
        if (s >= (unsigned)n) s = 0;
        pv[j] = (dv[j] << 16) | s;
        lo[j] = (int)atomicAdd(&lhist[dv[j] >> BSH], 1u);
      }
    }
    __syncthreads();
    // claim global runs: one atomic per non-empty bucket, padded lines (1 int / 64B)
    if (t < NB) {
      unsigned cc = lhist[t];
      gbase[t] = cc ? (unsigned)atomicAdd(&bcur[t << 4], (int)cc) : 0u;
    }
    __syncthreads();
    // write runs (block-claimed arena ranges; lines stay mostly in one L2)
#pragma unroll
    for (int j = 0; j < 16; j++) {
      unsigned d = pv[j] >> 16;
      if (d < (unsigned)n) {
        unsigned bkt = d >> BSH;
        unsigned pos = gbase[bkt] + (unsigned)lo[j];
        if (pos < (unsigned)BCAP) arena[(bkt << 13) + pos] = pv[j];
        else { int kk2 = atomicAdd(ovf_cnt, 1); if (kk2 < e) ovf[kk2] = make_int2((int)d, (int)(pv[j] & 0xFFFFu)); }
      }
    }
  }
}

// ---------------- bucket -> node-major ed lists (coalesced writes), sets cursor ---------
__global__ __launch_bounds__(256) void sortb_k(const unsigned int* __restrict__ arena,
                                               const int* __restrict__ bcur,
                                               int* __restrict__ cursor,
                                               unsigned short* __restrict__ ed,
                                               int2* __restrict__ ovf,
                                               int* __restrict__ ovf_cnt,
                                               int n, int e) {
  int bk = blockIdx.x;
  __shared__ unsigned short edL[256][32];   // 16 KB node-major image
  __shared__ unsigned int deg[256];
  int t = threadIdx.x;
  int total = bcur[bk << 4];
  int cnt = min(total, BCAP);
  bool spilled = total > BCAP;
  deg[t] = 0;
  __syncthreads();
  int node0 = bk << BSH;
  for (int i = t; i < cnt; i += 256) {
    unsigned pv = arena[((unsigned)bk << 13) + i];
    int d8 = (int)((pv >> 16) & 255);
    unsigned s = pv & 0xFFFFu;
    unsigned slot = atomicAdd(&deg[d8], 1u);
    if (slot < 32) edL[d8][slot] = (unsigned short)s;
    else { int kk = atomicAdd(ovf_cnt, 1); if (kk < e) ovf[kk] = make_int2(node0 + d8, (int)s); }
  }
  __syncthreads();
  int lim = n - node0; if (lim > 256) lim = 256;
  if (lim <= 0) return;
  const uint4* edv = (const uint4*)&edL[0][0];
  for (int j = t; j < (lim << 2); j += 256)     // 4x uint4 per 64B row, contiguous
    *(uint4*)(ed + ((size_t)node0 << 5) + ((size_t)j << 3)) = edv[j];
  if (t < lim)
    cursor[node0 + t] = (int)deg[t] + (spilled ? (1 << 20) : 0);
}

// ---------------- wave-per-node two-phase softmax aggregate; register-staged gather -----
// ALL independent loads (cursor, ed, a_dst, bias, flag) issued at wave start.
__global__ __launch_bounds__(512) void agg_k(const unsigned short* __restrict__ hfeat,
                                             const int* __restrict__ cursor,
                                             const unsigned short* __restrict__ ed,
                                             const int2* __restrict__ ovf,
                                             const int* __restrict__ ovf_cnt,
                                             const float* __restrict__ a_src,
                                             const float* __restrict__ a_dst,
                                             const float* __restrict__ bias_f,
                                             const int* __restrict__ flag,
                                             void* __restrict__ outv, int n, int e) {
  int wave = threadIdx.x >> 6;
  int l = threadIdx.x & 63;
  int node = (blockIdx.x << 3) + wave;
  if (node >= n) return;
  int hq = l & 3;          // weight-phase head (slots l>>2 and 16+(l>>2))
  int c8 = l & 15;         // gather col group
  int hg = c8 >> 2;        // gather-phase head
  int q = l >> 4;          // quarter
  // five independent loads issued together (none depends on another)
  int total = cursor[node];
  int edv = (l < 32) ? (int)ed[(node << 5) + l] : 0;
  float4 ad4 = *(const float4*)&a_dst[node << 2];
  float4 bi0 = *(const float4*)&bias_f[c8 << 3];
  float4 bi1 = *(const float4*)&bias_f[(c8 << 3) + 4];
  int isf32 = *flag;

  int sdeg = total & 0xFFFFF;        // low bits = stored degree; bit20 = bucket spilled
  int cnt0 = min(sdeg, 32);
  float adq = (hq == 0) ? ad4.x : (hq == 1) ? ad4.y : (hq == 2) ? ad4.z : ad4.w;

  float m_run = -3.0e38f;
  float swacc = 0.f;
  float acc[8];
#pragma unroll
  for (int k = 0; k < 8; k++) acc[k] = 0.f;

  if (cnt0 > 0) {
    int srcv = (l < cnt0) ? edv : 0;   // zero garbage slots (keeps h-row-0 x 0 safety)
    int myslot = l >> 2;
    int ssA = __shfl(srcv, myslot, 64);
    int ssB = __shfl(srcv, myslot + 16, 64);
    // issue a_src logit loads (2 per lane)
    float asA = (myslot < cnt0) ? a_src[(ssA << 2) + hq] : 0.f;
    float asB = (myslot + 16 < cnt0) ? a_src[(ssB << 2) + hq] : 0.f;
    // issue ALL h-row gathers now — they only depend on indices, and fly
    // under the softmax math below (up to 8 outstanding 16B loads/lane)
    uint4 hv[8];
    int njs = (cnt0 + 3) >> 2;  // wave-uniform
#pragma unroll
    for (int j = 0; j < 8; j++) {
      if (j < njs) {
        int sj = __shfl(srcv, (j << 2) + q, 64);
        hv[j] = *(const uint4*)(hfeat + (((size_t)sj) << 7) + (c8 << 3));
      }
    }
    // softmax (waits only on a_src loads)
    float zA = -3.0e38f, zB = -3.0e38f;
    if (myslot < cnt0) {
      float zz = asA + adq;
      zA = zz > 0.f ? zz : NEG_SLOPE * zz;
    }
    if (myslot + 16 < cnt0) {
      float zz = asB + adq;
      zB = zz > 0.f ? zz : NEG_SLOPE * zz;
    }
    float cm = fmaxf(zA, zB);
    cm = fmaxf(cm, __shfl_xor(cm, 4, 64));
    cm = fmaxf(cm, __shfl_xor(cm, 8, 64));
    cm = fmaxf(cm, __shfl_xor(cm, 16, 64));
    cm = fmaxf(cm, __shfl_xor(cm, 32, 64));
    float wexpA = (myslot < cnt0) ? __expf(zA - cm) : 0.f;
    float wexpB = (myslot + 16 < cnt0) ? __expf(zB - cm) : 0.f;
    m_run = cm;
    swacc = wexpA + wexpB;
    // fma from registers (waits on hv)
#pragma unroll
    for (int j = 0; j < 8; j++) {
      if (j < njs) {
        int eidx = (j << 2) + q;
        float sw = (j < 4) ? __shfl(wexpA, (eidx << 2) | hg, 64)
                           : __shfl(wexpB, ((eidx - 16) << 2) | hg, 64);
        unsigned uu[4] = {hv[j].x, hv[j].y, hv[j].z, hv[j].w};
#pragma unroll
        for (int k2 = 0; k2 < 4; k2++) {
          acc[2 * k2]     = fmaf(sw, bf2f((unsigned short)(uu[k2] & 0xffffu)), acc[2 * k2]);
          acc[2 * k2 + 1] = fmaf(sw, bf2f((unsigned short)(uu[k2] >> 16)), acc[2 * k2 + 1]);
        }
      }
    }
  }

  // ---- overflow scan (rare: deg > 32 or bucket spill), online merge ----
  if (total > 32) {
    int K = *ovf_cnt;
    if (K > e) K = e;
    for (int c0 = 0; c0 < K; c0 += 16) {
      int sv = 0, dv = -1;
      if (l < 16 && (c0 + l) < K) { int2 pr = ovf[c0 + l]; dv = pr.x; sv = pr.y; }
      int myslot = l >> 2;
      int dmy = __shfl(dv, myslot, 64);
      int smy = __shfl(sv, myslot, 64);
      bool valid = (dmy == node);
      float z = -3.0e38f;
      if (valid) {
        float zz = a_src[(smy << 2) + hq] + adq;
        z = zz > 0.f ? zz : NEG_SLOPE * zz;
      }
      float cm = z;
      cm = fmaxf(cm, __shfl_xor(cm, 4, 64));
      cm = fmaxf(cm, __shfl_xor(cm, 8, 64));
      cm = fmaxf(cm, __shfl_xor(cm, 16, 64));
      cm = fmaxf(cm, __shfl_xor(cm, 32, 64));
      float m_new = fmaxf(m_run, cm);
      float resc_q = __expf(m_run - m_new);
      m_run = m_new;
      float wexp = valid ? __expf(z - m_new) : 0.f;
      swacc = swacc * resc_q + wexp;
      float resc_h = __shfl(resc_q, hg, 64);
#pragma unroll
      for (int k = 0; k < 8; k++) acc[k] *= resc_h;
#pragma unroll
      for (int js = 0; js < 4; js++) {
        int eidx = (js << 2) + q;
        float sw = __shfl(wexp, (eidx << 2) | hg, 64);
        int sj = __shfl(sv, eidx, 64);
        uint4 hv = *(const uint4*)(hfeat + (((size_t)sj) << 7) + (c8 << 3));
        unsigned uu[4] = {hv.x, hv.y, hv.z, hv.w};
#pragma unroll
        for (int k2 = 0; k2 < 4; k2++) {
          acc[2 * k2]     = fmaf(sw, bf2f((unsigned short)(uu[k2] & 0xffffu)), acc[2 * k2]);
          acc[2 * k2 + 1] = fmaf(sw, bf2f((unsigned short)(uu[k2] >> 16)), acc[2 * k2 + 1]);
        }
      }
    }
  }

  // per-head exp-sum over the 16 lanes sharing hq
  for (int m = 4; m < 64; m <<= 1) swacc += __shfl_xor(swacc, m, 64);
  // cross-quarter accumulator reduce
#pragma unroll
  for (int k = 0; k < 8; k++) {
    acc[k] += __shfl_xor(acc[k], 16, 64);
    acc[k] += __shfl_xor(acc[k], 32, 64);
  }
  float sumv = __shfl(swacc, hg, 64);
  float rs = 1.f / (sumv + EPSF);
  if (l < 16) {
    float bb[8] = {bi0.x, bi0.y, bi0.z, bi0.w, bi1.x, bi1.y, bi1.z, bi1.w};
    float o[8];
#pragma unroll
    for (int k = 0; k < 8; k++) o[k] = fmaf(acc[k], rs, bb[k]);
    size_t base = (((size_t)node) << 7) + (c8 << 3);
    if (isf32) {
      *(float4*)((float*)outv + base)     = make_float4(o[0], o[1], o[2], o[3]);
      *(float4*)((float*)outv + base + 4) = make_float4(o[4], o[5], o[6], o[7]);
    } else {
      uint4 pk;
      pk.x = (unsigned)f2bf(o[0]) | ((unsigned)f2bf(o[1]) << 16);
      pk.y = (unsigned)f2bf(o[2]) | ((unsigned)f2bf(o[3]) << 16);
      pk.z = (unsigned)f2bf(o[4]) | ((unsigned)f2bf(o[5]) << 16);
      pk.w = (unsigned)f2bf(o[6]) | ((unsigned)f2bf(o[7]) << 16);
      *(uint4*)((unsigned short*)outv + base) = pk;
    }
  }
}

extern "C" void kernel_launch(void* const* d_in, const int* in_sizes, int n_in,
                              void* d_out, int out_size, void* d_ws, size_t ws_size,
                              hipStream_t stream) {
  const void* x    = d_in[0];
  const int*  ei   = (const int*)d_in[1];
  const void* w    = d_in[2];
  const void* att  = d_in[3];
  const void* bias = d_in[4];

  const int n = in_sizes[0] / 256;
  const int e = in_sizes[1] / 2;
  const int NB = (n + 255) / 256;            // dst buckets (n < 65536)
  const int zb = (NB * 16 + 255) / 256;      // padded-cursor-zero blocks
  const int gb = (n + 127) / 128;            // gemm blocks (dispatched first)
  const int fb = (e + 4095) / 4096;          // fill blocks: one 4096-edge chunk each

  char* p = (char*)d_ws;
  size_t off = 0;
  auto carve = [&](size_t bytes) -> void* {
    void* r = p + off;
    off = (off + bytes + 255) & ~(size_t)255;
    return r;
  };
  int*      flag    = (int*)carve(sizeof(int));
  int*      ovf_cnt = (int*)carve(sizeof(int));
  float*    bias_f  = (float*)carve(128 * 4);
  unsigned short* h = (unsigned short*)carve((size_t)n * 128 * 2);   // 12.8 MB
  float*    a_src   = (float*)carve((size_t)n * 4 * 4);
  float*    a_dst   = (float*)carve((size_t)n * 4 * 4);
  int*      bcur    = (int*)carve((size_t)NB * 16 * 4);              // padded: 1 int / 64B
  unsigned int* arena = (unsigned int*)carve((size_t)NB * BCAP * 4); // 6.4 MB
  int*      cursor  = (int*)carve((size_t)n * 4);
  unsigned short* ed = (unsigned short*)carve((size_t)n * 32 * 2);   // 3.2 MB
  int2*     ovf     = (int2*)carve((size_t)e * 8);                   // 6.4 MB
  unsigned short* bpack = (unsigned short*)carve((size_t)256 * 128 * 2);  // 64 KB
  unsigned short* wpack = (unsigned short*)carve((size_t)8 * 64 * 8 * 2); // 8 KB
  (void)ws_size;

  prep_k<<<zb + 145, 256, 0, stream>>>((const unsigned short*)x, w, att, bias,
                                       flag, bcur, ovf_cnt, bpack, wpack, bias_f,
                                       NB * 16, zb);
  gemmfill_k<<<gb + fb, 256, 0, stream>>>(x, flag, bpack, wpack, h, a_src, a_dst,
                                          ei, bcur, arena, ovf, ovf_cnt, n, e, gb, fb);
  sortb_k<<<NB, 256, 0, stream>>>(arena, bcur, cursor, ed, ovf, ovf_cnt, n, e);
  agg_k<<<(n + 7) / 8, 512, 0, stream>>>(h, cursor, ed, ovf, ovf_cnt, a_src, a_dst,
                                         bias_f, flag, d_out, n, e);
}

// Round 14
// 162.854 us; speedup vs baseline: 1.0535x; 1.0535x over previous
//
#include <hip/hip_runtime.h>
#include <hip/hip_bf16.h>

#define NEG_SLOPE 0.2f
#define EPSF 1e-16f
#define BSH 8           // 256 nodes per bucket
#define BCAP 8192       // per-bucket arena capacity (u32 pairs)

typedef __attribute__((ext_vector_type(8))) short short8;     // 8 bf16 = 4 VGPR
typedef __attribute__((ext_vector_type(4))) float floatx4;    // MFMA acc

__device__ __forceinline__ float bf2f(unsigned short u) {
  union { unsigned int i; float f; } v; v.i = ((unsigned int)u) << 16; return v.f;
}
__device__ __forceinline__ unsigned short f2bf(float f) {
  union { float f; unsigned int i; } v; v.f = f;
  unsigned int r = v.i + 0x7fffu + ((v.i >> 16) & 1u);  // RNE
  return (unsigned short)(r >> 16);
}

// ---------------- merged prep: zero padded bucket cursors | detect+pack -----------------
__global__ __launch_bounds__(256) void prep_k(const unsigned short* __restrict__ xw,
                                              const void* __restrict__ w,
                                              const void* __restrict__ att,
                                              const void* __restrict__ bias,
                                              int* __restrict__ flag,
                                              int* __restrict__ bcur,
                                              int* __restrict__ ovf_cnt,
                                              unsigned short* __restrict__ bpack,
                                              unsigned short* __restrict__ wpack,
                                              float* __restrict__ bias_f,
                                              int nb16, int zb) {
  int b = blockIdx.x;
  if (b < zb) {
    int i = b * 256 + threadIdx.x;
    if (i < nb16) bcur[i] = 0;
    if (i == 0) *ovf_cnt = 0;
    return;
  }
  __shared__ int cnt;
  if (threadIdx.x == 0) cnt = 0;
  __syncthreads();
  // sample the 16 even bf16s of this thread's 64B span via 4 vector loads
  int local = 0;
  const uint4* xv4 = (const uint4*)(xw + threadIdx.x * 32);
#pragma unroll
  for (int k2 = 0; k2 < 4; k2++) {
    uint4 u = xv4[k2];
    unsigned uu[4] = {u.x, u.y, u.z, u.w};
#pragma unroll
    for (int q2 = 0; q2 < 4; q2++) {
      int ex = ((uu[q2] & 0xffffu) >> 7) & 0xFF;
      if (ex >= 0x90 || ex <= 0x40) local++;
    }
  }
  atomicAdd(&cnt, local);
  __syncthreads();
  int f32 = (cnt > 256) ? 1 : 0;
  int pb = b - zb;
  if (pb == 0 && threadIdx.x == 0) *flag = f32;
  if (pb < 128) {
    int i = pb * 256 + threadIdx.x;  // 0..32767
    int j = i & 7, lane = (i >> 3) & 63, nt = (i >> 9) & 7, kb = i >> 12;
    int f = (kb << 5) + ((lane >> 4) << 3) + j;
    int col = (nt << 4) + (lane & 15);
    int src = ((col >> 5) << 13) + (f << 5) + (col & 31);
    float v = f32 ? ((const float*)w)[src] : bf2f(((const unsigned short*)w)[src]);
    bpack[i] = f2bf(v);
  } else if (pb < 144) {
    int i = (pb - 128) * 256 + threadIdx.x;  // 0..4095
    int j = i & 7, lane = (i >> 3) & 63, kb = i >> 9;
    int quad = lane >> 4, m16 = lane & 15;
    int f = (kb << 5) + (quad << 3) + j;
    float v = 0.f;
    if (m16 < 8) {
      int hd = m16 & 3;
      int db = (m16 >= 4) ? 32 : 0;
      int wbase = (hd << 13) + (f << 5);
      int abase = (hd << 6) + db;
      float acc = 0.f;
      for (int c = 0; c < 32; c++) {
        float wv = f32 ? ((const float*)w)[wbase + c] : bf2f(((const unsigned short*)w)[wbase + c]);
        float av = f32 ? ((const float*)att)[abase + c] : bf2f(((const unsigned short*)att)[abase + c]);
        acc = fmaf(wv, av, acc);
      }
      v = acc;
    }
    wpack[i] = f2bf(v);
  } else {
    int i = threadIdx.x;
    if (i < 128) bias_f[i] = f32 ? ((const float*)bias)[i] : bf2f(((const unsigned short*)bias)[i]);
  }
}

// ---------------- fused: bf16-MFMA gemm+attlogits (blocks<gb) | bucket-run fill ---------
// bf16 path: ALL 16 x-fragment loads hoisted to registers (single vmcnt drain instead of
// 8 serial HBM round-trips per wave; dispatch-limited occupancy so +VGPR is free).
__global__ __launch_bounds__(256) void gemmfill_k(const void* __restrict__ xv,
                                                  const int* __restrict__ flag,
                                                  const unsigned short* __restrict__ bpack,
                                                  const unsigned short* __restrict__ wpack,
                                                  unsigned short* __restrict__ h,
                                                  float* __restrict__ a_srcp,
                                                  float* __restrict__ a_dstp,
                                                  const int* __restrict__ ei,
                                                  int* __restrict__ bcur,
                                                  unsigned int* __restrict__ arena,
                                                  int2* __restrict__ ovf,
                                                  int* __restrict__ ovf_cnt,
                                                  int n, int e, int gb, int fb) {
  int b = blockIdx.x;
  if (b < gb) {
    int t = threadIdx.x;
    int wave = t >> 6, l = t & 63;
    int quad = l >> 4, m16 = l & 15;
    long n0 = (long)b * 128 + wave * 32;
    int isf32 = *flag;

    floatx4 acc[2][8];
    floatx4 acca[2];
#pragma unroll
    for (int mt = 0; mt < 2; mt++) {
      acca[mt] = (floatx4){0.f, 0.f, 0.f, 0.f};
#pragma unroll
      for (int nt = 0; nt < 8; nt++) acc[mt][nt] = (floatx4){0.f, 0.f, 0.f, 0.f};
    }

    long rowA = n0 + m16;      if (rowA >= n) rowA = n - 1;   // clamp; discarded at store
    long rowB = n0 + 16 + m16; if (rowB >= n) rowB = n - 1;

    if (!isf32) {
      // ---- bf16: hoist ALL x loads (16 x 16B per lane), fully unrolled K loop ----
      short8 axr[8][2];
#pragma unroll
      for (int kb = 0; kb < 8; kb++) {
        axr[kb][0] = *(const short8*)((const unsigned short*)xv + (rowA << 8) + (kb << 5) + (quad << 3));
        axr[kb][1] = *(const short8*)((const unsigned short*)xv + (rowB << 8) + (kb << 5) + (quad << 3));
      }
#pragma unroll
      for (int kb = 0; kb < 8; kb++) {
        short8 wfr = *(const short8*)(wpack + (((kb << 6) + l) << 3));
        acca[0] = __builtin_amdgcn_mfma_f32_16x16x32_bf16(axr[kb][0], wfr, acca[0], 0, 0, 0);
        acca[1] = __builtin_amdgcn_mfma_f32_16x16x32_bf16(axr[kb][1], wfr, acca[1], 0, 0, 0);
#pragma unroll
        for (int nt = 0; nt < 8; nt++) {
          short8 bfr = *(const short8*)(bpack + (((kb << 3) + nt) << 9) + (l << 3));
          acc[0][nt] = __builtin_amdgcn_mfma_f32_16x16x32_bf16(axr[kb][0], bfr, acc[0][nt], 0, 0, 0);
          acc[1][nt] = __builtin_amdgcn_mfma_f32_16x16x32_bf16(axr[kb][1], bfr, acc[1][nt], 0, 0, 0);
        }
      }
    } else {
      // ---- f32: keep prefetch-1 structure (full hoist would spill) ----
      auto load_afr = [&](int kb, short8* dst) {
        long rows[2] = {rowA, rowB};
#pragma unroll
        for (int mt = 0; mt < 2; mt++) {
          const float* xp = (const float*)xv + (rows[mt] << 8) + (kb << 5) + (quad << 3);
          float4 u0 = *(const float4*)xp;
          float4 u1 = *(const float4*)(xp + 4);
          short8 a;
          a[0] = (short)f2bf(u0.x); a[1] = (short)f2bf(u0.y);
          a[2] = (short)f2bf(u0.z); a[3] = (short)f2bf(u0.w);
          a[4] = (short)f2bf(u1.x); a[5] = (short)f2bf(u1.y);
          a[6] = (short)f2bf(u1.z); a[7] = (short)f2bf(u1.w);
          dst[mt] = a;
        }
      };
      short8 afr[2], afn[2];
      load_afr(0, afr);
      for (int kb = 0; kb < 8; kb++) {
        short8 wfr = *(const short8*)(wpack + (((kb << 6) + l) << 3));
        short8 bfr[8];
#pragma unroll
        for (int nt = 0; nt < 8; nt++)
          bfr[nt] = *(const short8*)(bpack + (((kb << 3) + nt) << 9) + (l << 3));
        if (kb < 7) load_afr(kb + 1, afn);
        acca[0] = __builtin_amdgcn_mfma_f32_16x16x32_bf16(afr[0], wfr, acca[0], 0, 0, 0);
        acca[1] = __builtin_amdgcn_mfma_f32_16x16x32_bf16(afr[1], wfr, acca[1], 0, 0, 0);
#pragma unroll
        for (int nt = 0; nt < 8; nt++) {
          acc[0][nt] = __builtin_amdgcn_mfma_f32_16x16x32_bf16(afr[0], bfr[nt], acc[0][nt], 0, 0, 0);
          acc[1][nt] = __builtin_amdgcn_mfma_f32_16x16x32_bf16(afr[1], bfr[nt], acc[1][nt], 0, 0, 0);
        }
        afr[0] = afn[0]; afr[1] = afn[1];
      }
    }
#pragma unroll
    for (int mt = 0; mt < 2; mt++)
#pragma unroll
      for (int r = 0; r < 4; r++) {
        long row = n0 + mt * 16 + quad * 4 + r;
        if (row < n) {
#pragma unroll
          for (int nt = 0; nt < 8; nt++)
            h[(row << 7) + (nt << 4) + m16] = f2bf(acc[mt][nt][r]);
          if (m16 < 8) {
            float val = acca[mt][r];
            int hd = m16 & 3;
            if (m16 < 4) a_srcp[(row << 2) + hd] = val;
            else         a_dstp[(row << 2) + hd] = val;
          }
        }
      }
  } else {
    // -------- bucket-run fill: chunk = 4096 edges, 256-node buckets --------
    const int NB = (n + 255) >> BSH;        // <= 256 (n < 65536)
    __shared__ unsigned int lhist[256];
    __shared__ unsigned int gbase[256];
    int t = threadIdx.x;
    int c = b - gb;
    if (t < NB) lhist[t] = 0;
    __syncthreads();
    int e0 = c << 12;
    // issue ALL 32 edge loads upfront (dst+src unconditional, independent chains)
    unsigned dv[16]; int sv[16];
#pragma unroll
    for (int j = 0; j < 16; j++) {
      int i = e0 + (j << 8) + t;
      dv[j] = 0xFFFFFFFFu; sv[j] = 0;
      if (i < e) { dv[j] = (unsigned)ei[e + i]; sv[j] = ei[i]; }
    }
    unsigned pv[16];
    int lo[16];
#pragma unroll
    for (int j = 0; j < 16; j++) {
      pv[j] = 0xFFFF0000u;                  // invalid marker (d = 0xFFFF >= n)
      lo[j] = 0;
      if (dv[j] < (unsigned)n) {
        unsigned s = (unsigned)sv[j];
        if (s >= (unsigned)n) s = 0;
        pv[j] = (dv[j] << 16) | s;
        lo[j] = (int)atomicAdd(&lhist[dv[j] >> BSH], 1u);
      }
    }
    __syncthreads();
    // claim global runs: one atomic per non-empty bucket, padded lines (1 int / 64B)
    if (t < NB) {
      unsigned cc = lhist[t];
      gbase[t] = cc ? (unsigned)atomicAdd(&bcur[t << 4], (int)cc) : 0u;
    }
    __syncthreads();
    // write runs (block-claimed arena ranges; lines stay mostly in one L2)
#pragma unroll
    for (int j = 0; j < 16; j++) {
      unsigned d = pv[j] >> 16;
      if (d < (unsigned)n) {
        unsigned bkt = d >> BSH;
        unsigned pos = gbase[bkt] + (unsigned)lo[j];
        if (pos < (unsigned)BCAP) arena[(bkt << 13) + pos] = pv[j];
        else { int kk2 = atomicAdd(ovf_cnt, 1); if (kk2 < e) ovf[kk2] = make_int2((int)d, (int)(pv[j] & 0xFFFFu)); }
      }
    }
  }
}

// ---------------- bucket -> node-major ed lists (coalesced writes), sets cursor ---------
__global__ __launch_bounds__(256) void sortb_k(const unsigned int* __restrict__ arena,
                                               const int* __restrict__ bcur,
                                               int* __restrict__ cursor,
                                               unsigned short* __restrict__ ed,
                                               int2* __restrict__ ovf,
                                               int* __restrict__ ovf_cnt,
                                               int n, int e) {
  int bk = blockIdx.x;
  __shared__ unsigned short edL[256][32];   // 16 KB node-major image
  __shared__ unsigned int deg[256];
  int t = threadIdx.x;
  int total = bcur[bk << 4];
  int cnt = min(total, BCAP);
  bool spilled = total > BCAP;
  deg[t] = 0;
  __syncthreads();
  int node0 = bk << BSH;
  for (int i = t; i < cnt; i += 256) {
    unsigned pv = arena[((unsigned)bk << 13) + i];
    int d8 = (int)((pv >> 16) & 255);
    unsigned s = pv & 0xFFFFu;
    unsigned slot = atomicAdd(&deg[d8], 1u);
    if (slot < 32) edL[d8][slot] = (unsigned short)s;
    else { int kk = atomicAdd(ovf_cnt, 1); if (kk < e) ovf[kk] = make_int2(node0 + d8, (int)s); }
  }
  __syncthreads();
  int lim = n - node0; if (lim > 256) lim = 256;
  if (lim <= 0) return;
  const uint4* edv = (const uint4*)&edL[0][0];
  for (int j = t; j < (lim << 2); j += 256)     // 4x uint4 per 64B row, contiguous
    *(uint4*)(ed + ((size_t)node0 << 5) + ((size_t)j << 3)) = edv[j];
  if (t < lim)
    cursor[node0 + t] = (int)deg[t] + (spilled ? (1 << 20) : 0);
}

// ---------------- wave-per-node two-phase softmax aggregate; register-staged gather -----
// loads ordered to maximize memory-level parallelism: cursor|ed|a_dst together,
// then a_src logits + h-row gathers in flight under the softmax VALU work.
// NOTE: bias/flag loads stay in the epilogue — hoisting them (R13) made the register
// allocator serialize the 8 outstanding h-gathers (VGPR 72->44, agg 40->47 us).
__global__ __launch_bounds__(512) void agg_k(const unsigned short* __restrict__ hfeat,
                                             const int* __restrict__ cursor,
                                             const unsigned short* __restrict__ ed,
                                             const int2* __restrict__ ovf,
                                             const int* __restrict__ ovf_cnt,
                                             const float* __restrict__ a_src,
                                             const float* __restrict__ a_dst,
                                             const float* __restrict__ bias_f,
                                             const int* __restrict__ flag,
                                             void* __restrict__ outv, int n, int e) {
  int wave = threadIdx.x >> 6;
  int l = threadIdx.x & 63;
  int node = (blockIdx.x << 3) + wave;
  if (node >= n) return;
  // three independent loads issued together (ed address does not depend on cursor)
  int total = cursor[node];
  int edv = (l < 32) ? (int)ed[(node << 5) + l] : 0;
  float4 ad4 = *(const float4*)&a_dst[node << 2];

  int sdeg = total & 0xFFFFF;        // low bits = stored degree; bit20 = bucket spilled
  int cnt0 = min(sdeg, 32);
  int hq = l & 3;          // weight-phase head (slots l>>2 and 16+(l>>2))
  int c8 = l & 15;         // gather col group
  int hg = c8 >> 2;        // gather-phase head
  int q = l >> 4;          // quarter
  float adq = (hq == 0) ? ad4.x : (hq == 1) ? ad4.y : (hq == 2) ? ad4.z : ad4.w;

  float m_run = -3.0e38f;
  float swacc = 0.f;
  float acc[8];
#pragma unroll
  for (int k = 0; k < 8; k++) acc[k] = 0.f;

  if (cnt0 > 0) {
    int srcv = (l < cnt0) ? edv : 0;   // zero garbage slots (keeps h-row-0 x 0 safety)
    int myslot = l >> 2;
    int ssA = __shfl(srcv, myslot, 64);
    int ssB = __shfl(srcv, myslot + 16, 64);
    // issue a_src logit loads (2 per lane)
    float asA = (myslot < cnt0) ? a_src[(ssA << 2) + hq] : 0.f;
    float asB = (myslot + 16 < cnt0) ? a_src[(ssB << 2) + hq] : 0.f;
    // issue ALL h-row gathers now — they only depend on indices, and fly
    // under the softmax math below (up to 8 outstanding 16B loads/lane)
    uint4 hv[8];
    int njs = (cnt0 + 3) >> 2;  // wave-uniform
#pragma unroll
    for (int j = 0; j < 8; j++) {
      if (j < njs) {
        int sj = __shfl(srcv, (j << 2) + q, 64);
        hv[j] = *(const uint4*)(hfeat + (((size_t)sj) << 7) + (c8 << 3));
      }
    }
    // softmax (waits only on a_src loads)
    float zA = -3.0e38f, zB = -3.0e38f;
    if (myslot < cnt0) {
      float zz = asA + adq;
      zA = zz > 0.f ? zz : NEG_SLOPE * zz;
    }
    if (myslot + 16 < cnt0) {
      float zz = asB + adq;
      zB = zz > 0.f ? zz : NEG_SLOPE * zz;
    }
    float cm = fmaxf(zA, zB);
    cm = fmaxf(cm, __shfl_xor(cm, 4, 64));
    cm = fmaxf(cm, __shfl_xor(cm, 8, 64));
    cm = fmaxf(cm, __shfl_xor(cm, 16, 64));
    cm = fmaxf(cm, __shfl_xor(cm, 32, 64));
    float wexpA = (myslot < cnt0) ? __expf(zA - cm) : 0.f;
    float wexpB = (myslot + 16 < cnt0) ? __expf(zB - cm) : 0.f;
    m_run = cm;
    swacc = wexpA + wexpB;
    // fma from registers (waits on hv)
#pragma unroll
    for (int j = 0; j < 8; j++) {
      if (j < njs) {
        int eidx = (j << 2) + q;
        float sw = (j < 4) ? __shfl(wexpA, (eidx << 2) | hg, 64)
                           : __shfl(wexpB, ((eidx - 16) << 2) | hg, 64);
        unsigned uu[4] = {hv[j].x, hv[j].y, hv[j].z, hv[j].w};
#pragma unroll
        for (int k2 = 0; k2 < 4; k2++) {
          acc[2 * k2]     = fmaf(sw, bf2f((unsigned short)(uu[k2] & 0xffffu)), acc[2 * k2]);
          acc[2 * k2 + 1] = fmaf(sw, bf2f((unsigned short)(uu[k2] >> 16)), acc[2 * k2 + 1]);
        }
      }
    }
  }

  // ---- overflow scan (rare: deg > 32 or bucket spill), online merge ----
  if (total > 32) {
    int K = *ovf_cnt;
    if (K > e) K = e;
    for (int c0 = 0; c0 < K; c0 += 16) {
      int sv = 0, dv = -1;
      if (l < 16 && (c0 + l) < K) { int2 pr = ovf[c0 + l]; dv = pr.x; sv = pr.y; }
      int myslot = l >> 2;
      int dmy = __shfl(dv, myslot, 64);
      int smy = __shfl(sv, myslot, 64);
      bool valid = (dmy == node);
      float z = -3.0e38f;
      if (valid) {
        float zz = a_src[(smy << 2) + hq] + adq;
        z = zz > 0.f ? zz : NEG_SLOPE * zz;
      }
      float cm = z;
      cm = fmaxf(cm, __shfl_xor(cm, 4, 64));
      cm = fmaxf(cm, __shfl_xor(cm, 8, 64));
      cm = fmaxf(cm, __shfl_xor(cm, 16, 64));
      cm = fmaxf(cm, __shfl_xor(cm, 32, 64));
      float m_new = fmaxf(m_run, cm);
      float resc_q = __expf(m_run - m_new);
      m_run = m_new;
      float wexp = valid ? __expf(z - m_new) : 0.f;
      swacc = swacc * resc_q + wexp;
      float resc_h = __shfl(resc_q, hg, 64);
#pragma unroll
      for (int k = 0; k < 8; k++) acc[k] *= resc_h;
#pragma unroll
      for (int js = 0; js < 4; js++) {
        int eidx = (js << 2) + q;
        float sw = __shfl(wexp, (eidx << 2) | hg, 64);
        int sj = __shfl(sv, eidx, 64);
        uint4 hv = *(const uint4*)(hfeat + (((size_t)sj) << 7) + (c8 << 3));
        unsigned uu[4] = {hv.x, hv.y, hv.z, hv.w};
#pragma unroll
        for (int k2 = 0; k2 < 4; k2++) {
          acc[2 * k2]     = fmaf(sw, bf2f((unsigned short)(uu[k2] & 0xffffu)), acc[2 * k2]);
          acc[2 * k2 + 1] = fmaf(sw, bf2f((unsigned short)(uu[k2] >> 16)), acc[2 * k2 + 1]);
        }
      }
    }
  }

  // per-head exp-sum over the 16 lanes sharing hq
  for (int m = 4; m < 64; m <<= 1) swacc += __shfl_xor(swacc, m, 64);
  // cross-quarter accumulator reduce
#pragma unroll
  for (int k = 0; k < 8; k++) {
    acc[k] += __shfl_xor(acc[k], 16, 64);
    acc[k] += __shfl_xor(acc[k], 32, 64);
  }
  float sumv = __shfl(swacc, hg, 64);
  float rs = 1.f / (sumv + EPSF);
  if (l < 16) {
    float o[8];
#pragma unroll
    for (int k = 0; k < 8; k++) o[k] = fmaf(acc[k], rs, bias_f[(c8 << 3) + k]);
    size_t base = (((size_t)node) << 7) + (c8 << 3);
    if (*flag) {
      *(float4*)((float*)outv + base)     = make_float4(o[0], o[1], o[2], o[3]);
      *(float4*)((float*)outv + base + 4) = make_float4(o[4], o[5], o[6], o[7]);
    } else {
      uint4 pk;
      pk.x = (unsigned)f2bf(o[0]) | ((unsigned)f2bf(o[1]) << 16);
      pk.y = (unsigned)f2bf(o[2]) | ((unsigned)f2bf(o[3]) << 16);
      pk.z = (unsigned)f2bf(o[4]) | ((unsigned)f2bf(o[5]) << 16);
      pk.w = (unsigned)f2bf(o[6]) | ((unsigned)f2bf(o[7]) << 16);
      *(uint4*)((unsigned short*)outv + base) = pk;
    }
  }
}

extern "C" void kernel_launch(void* const* d_in, const int* in_sizes, int n_in,
                              void* d_out, int out_size, void* d_ws, size_t ws_size,
                              hipStream_t stream) {
  const void* x    = d_in[0];
  const int*  ei   = (const int*)d_in[1];
  const void* w    = d_in[2];
  const void* att  = d_in[3];
  const void* bias = d_in[4];

  const int n = in_sizes[0] / 256;
  const int e = in_sizes[1] / 2;
  const int NB = (n + 255) / 256;            // dst buckets (n < 65536)
  const int zb = (NB * 16 + 255) / 256;      // padded-cursor-zero blocks
  const int gb = (n + 127) / 128;            // gemm blocks (dispatched first)
  const int fb = (e + 4095) / 4096;          // fill blocks: one 4096-edge chunk each

  char* p = (char*)d_ws;
  size_t off = 0;
  auto carve = [&](size_t bytes) -> void* {
    void* r = p + off;
    off = (off + bytes + 255) & ~(size_t)255;
    return r;
  };
  int*      flag    = (int*)carve(sizeof(int));
  int*      ovf_cnt = (int*)carve(sizeof(int));
  float*    bias_f  = (float*)carve(128 * 4);
  unsigned short* h = (unsigned short*)carve((size_t)n * 128 * 2);   // 12.8 MB
  float*    a_src   = (float*)carve((size_t)n * 4 * 4);
  float*    a_dst   = (float*)carve((size_t)n * 4 * 4);
  int*      bcur    = (int*)carve((size_t)NB * 16 * 4);              // padded: 1 int / 64B
  unsigned int* arena = (unsigned int*)carve((size_t)NB * BCAP * 4); // 6.4 MB
  int*      cursor  = (int*)carve((size_t)n * 4);
  unsigned short* ed = (unsigned short*)carve((size_t)n * 32 * 2);   // 3.2 MB
  int2*     ovf     = (int2*)carve((size_t)e * 8);                   // 6.4 MB
  unsigned short* bpack = (unsigned short*)carve((size_t)256 * 128 * 2);  // 64 KB
  unsigned short* wpack = (unsigned short*)carve((size_t)8 * 64 * 8 * 2); // 8 KB
  (void)ws_size;

  prep_k<<<zb + 145, 256, 0, stream>>>((const unsigned short*)x, w, att, bias,
                                       flag, bcur, ovf_cnt, bpack, wpack, bias_f,
                                       NB * 16, zb);
  gemmfill_k<<<gb + fb, 256, 0, stream>>>(x, flag, bpack, wpack, h, a_src, a_dst,
                                          ei, bcur, arena, ovf, ovf_cnt, n, e, gb, fb);
  sortb_k<<<NB, 256, 0, stream>>>(arena, bcur, cursor, ed, ovf, ovf_cnt, n, e);
  agg_k<<<(n + 7) / 8, 512, 0, stream>>>(h, cursor, ed, ovf, ovf_cnt, a_src, a_dst,
                                         bias_f, flag, d_out, n, e);
}